// Round 1
// baseline (485.764 us; speedup 1.0000x reference)
//
#include <hip/hip_runtime.h>
#include <stdint.h>

// SIREN MLP 3->256->256->256->256->3, N=524288 points, fp32 in/out.
// Hidden matmuls in bf16 MFMA (16x16x32), first/last layers fp32 VALU.
// Error budget: bf16 rounding ~0.3% rel of output << 2% threshold.

#define OMEGA 30.0f

typedef float  f32x4 __attribute__((ext_vector_type(4)));
typedef short  s16x8 __attribute__((ext_vector_type(8)));

__device__ __forceinline__ float bf16_to_f32(uint16_t u) {
    uint32_t b = ((uint32_t)u) << 16;
    return __builtin_bit_cast(float, b);
}
__device__ __forceinline__ uint16_t f32_to_bf16(float f) {
    uint32_t u = __builtin_bit_cast(uint32_t, f);
    u += 0x7FFFu + ((u >> 16) & 1u);   // RNE (values are finite/sane here)
    return (uint16_t)(u >> 16);
}

// Relayout W1..W3 (256x256 fp32, row-major (out,in)) -> bf16 chunk-major
// ws[l][kc][o][32]: chunk kc holds all 256 out-rows x 32 in-cols, contiguous
// 16KB per chunk so global_load_lds(16B/lane) staging is an identity copy.
__global__ void convert_weights(const float* __restrict__ W1,
                                const float* __restrict__ W2,
                                const float* __restrict__ W3,
                                uint16_t* __restrict__ wsb) {
    int tid = blockIdx.x * blockDim.x + threadIdx.x;   // 0..196607
    int l = tid >> 16;
    int r = tid & 65535;
    int o = r >> 8;
    int k = r & 255;
    const float* W = (l == 0) ? W1 : (l == 1) ? W2 : W3;
    float w = W[o * 256 + k];
    wsb[l * 65536 + (k >> 5) * 8192 + o * 32 + (k & 31)] = f32_to_bf16(w);
}

// Block: 256 threads = 4 waves, 64 points. Waves split the 256 output cols
// 4-ways (wave j -> cols 64j..64j+63), each wave covers all 64 rows (4 row
// tiles of 16). acc = 4x4 tiles x 4 f32 = 64 VGPRs.
// LDS: h[8][64][40] bf16 (40=32+8 pad keeps 16B alignment + bank balance)
//      = 40KB, W chunk [256][32] bf16 = 16KB. Total 56KB -> 2 blocks/CU.
__global__ __launch_bounds__(256, 2) void siren_main(
    const float* __restrict__ x,
    const float* __restrict__ W0, const float* __restrict__ b0,
    const float* __restrict__ b1, const float* __restrict__ b2,
    const float* __restrict__ b3,
    const float* __restrict__ W4, const float* __restrict__ b4,
    const uint16_t* __restrict__ Wb,   // [3][8][256][32] bf16
    float* __restrict__ out)
{
    __shared__ uint16_t h_lds[8 * 64 * 40];   // [kc][row][40], row stride 80B
    __shared__ uint16_t w_lds[256 * 32];      // [out_row][32], row stride 64B

    const int tid  = threadIdx.x;
    const int lane = tid & 63;
    const int wid  = tid >> 6;     // wave id = column-quarter j
    const int n16  = lane & 15;
    const int q    = lane >> 4;    // quad
    const int p0   = blockIdx.x * 64;

    // ---------------- Layer 0 (fp32 VALU): h1 = sin(30*(W0 x + b0)) --------
    {
        const int c = tid;                      // output channel
        float wa = W0[c * 3 + 0], wb = W0[c * 3 + 1], wc = W0[c * 3 + 2];
        float bb = b0[c];
        const int kc = c >> 5, cc = c & 31;
        for (int p = 0; p < 64; ++p) {
            // x addr is thread-uniform -> scalar loads, broadcast
            float x0 = x[(p0 + p) * 3 + 0];
            float x1 = x[(p0 + p) * 3 + 1];
            float x2 = x[(p0 + p) * 3 + 2];
            float z = OMEGA * (wa * x0 + wb * x1 + wc * x2 + bb);
            h_lds[kc * 2560 + p * 40 + cc] = f32_to_bf16(__sinf(z));
        }
    }

    // ---------------- Hidden layers 1..3 (bf16 MFMA) -----------------------
    for (int l = 0; l < 3; ++l) {
        f32x4 acc[4][4] = {};                      // [row_tile][col_tile]
        const uint16_t* Wl = Wb + l * 65536;

        for (int kc = 0; kc < 8; ++kc) {
            __syncthreads();   // prev kc done with w_lds; h writes visible
            // stage 16KB W chunk: 4 rounds x 256 threads x 16B, async to LDS
            {
                const uint16_t* src = Wl + kc * 8192;
                #pragma unroll
                for (int it = 0; it < 4; ++it) {
                    int idx = it * 256 + tid;          // x8 bf16 elems
                    __builtin_amdgcn_global_load_lds(
                        (const __attribute__((address_space(1))) void*)(src + idx * 8),
                        (__attribute__((address_space(3))) void*)&w_lds[(it * 256 + wid * 64) * 8],
                        16, 0, 0);
                }
            }
            __syncthreads();   // drains vmcnt incl. global_load_lds

            s16x8 a[4], b[4];
            #pragma unroll
            for (int rt = 0; rt < 4; ++rt)   // A: lane(m=n16,q) -> h[m][q*8+j]
                a[rt] = *(const s16x8*)&h_lds[kc * 2560 + (rt * 16 + n16) * 40 + q * 8];
            #pragma unroll
            for (int t = 0; t < 4; ++t)      // B: lane(n=n16,q) -> W[n][q*8+j]
                b[t] = *(const s16x8*)&w_lds[(wid * 64 + t * 16 + n16) * 32 + q * 8];
            #pragma unroll
            for (int rt = 0; rt < 4; ++rt)
                #pragma unroll
                for (int t = 0; t < 4; ++t)
                    acc[rt][t] = __builtin_amdgcn_mfma_f32_16x16x32_bf16(
                        a[rt], b[t], acc[rt][t], 0, 0, 0);
        }
        __syncthreads();   // all h_lds reads done before overwrite

        // epilogue: bias + sin, write bf16 back to h_lds for next layer
        const float* bl = (l == 0) ? b1 : (l == 1) ? b2 : b3;
        #pragma unroll
        for (int t = 0; t < 4; ++t) {
            int col = wid * 64 + t * 16 + n16;
            float bb = bl[col];
            int kc = col >> 5, cc = col & 31;
            #pragma unroll
            for (int rt = 0; rt < 4; ++rt)
                #pragma unroll
                for (int r = 0; r < 4; ++r) {
                    int row = rt * 16 + q * 4 + r;   // C/D: row=q*4+reg, col=n16
                    float z = acc[rt][t][r] + bb;
                    h_lds[kc * 2560 + row * 40 + cc] = f32_to_bf16(__sinf(z));
                }
        }
    }
    __syncthreads();

    // ---------------- Final layer (fp32 VALU): out = W4 h4 + b4 ------------
    if (tid < 192) {
        int p = tid & 63, o = tid >> 6;        // o is wave-uniform -> s_loads
        const float* w4 = W4 + o * 256;
        float sum = b4[o];
        for (int kc = 0; kc < 8; ++kc) {
            #pragma unroll
            for (int jj = 0; jj < 32; jj += 8) {
                s16x8 hv = *(const s16x8*)&h_lds[kc * 2560 + p * 40 + jj];
                #pragma unroll
                for (int e = 0; e < 8; ++e)
                    sum += bf16_to_f32((uint16_t)hv[e]) * w4[kc * 32 + jj + e];
            }
        }
        out[(p0 + p) * 3 + o] = sum;
    }
}

extern "C" void kernel_launch(void* const* d_in, const int* in_sizes, int n_in,
                              void* d_out, int out_size, void* d_ws, size_t ws_size,
                              hipStream_t stream) {
    const float* x  = (const float*)d_in[0];
    const float* W0 = (const float*)d_in[1];
    const float* b0 = (const float*)d_in[2];
    const float* W1 = (const float*)d_in[3];
    const float* b1 = (const float*)d_in[4];
    const float* W2 = (const float*)d_in[5];
    const float* b2 = (const float*)d_in[6];
    const float* W3 = (const float*)d_in[7];
    const float* b3 = (const float*)d_in[8];
    const float* W4 = (const float*)d_in[9];
    const float* b4 = (const float*)d_in[10];
    float* outp     = (float*)d_out;
    uint16_t* wsb   = (uint16_t*)d_ws;   // needs 3*65536*2 = 384KB

    hipLaunchKernelGGL(convert_weights, dim3(768), dim3(256), 0, stream,
                       W1, W2, W3, wsb);
    hipLaunchKernelGGL(siren_main, dim3(8192), dim3(256), 0, stream,
                       x, W0, b0, b1, b2, b3, W4, b4, wsb, outp);
}